// Round 5
// baseline (329.809 us; speedup 1.0000x reference)
//
#include <hip/hip_runtime.h>

#define BATCH   4096
#define SLOTS   26
#define MAX_NNZ 10
#define EMB     64
#define ROWS    (BATCH * SLOTS)   // 106,496 output rows

typedef float floatx4 __attribute__((ext_vector_type(4)));
typedef int   intx4   __attribute__((ext_vector_type(4)));
typedef int   intx2   __attribute__((ext_vector_type(2)));

// One output row [EMB=64 floats] is handled by 16 lanes, each owning one
// float4. A 64-lane wave processes 4 rows concurrently.
//
// - Branch-free masked-to-dummy gathers: masked entries redirect to table
//   row 0 (L1-resident broadcast) via cndmask on the index; all 10 gathers
//   stay in flight (queue-saturating MLP).
// - keys/mask loaded as int4/int2 vectors: 6 vmem insts instead of 20
//   scalar dwords per thread (the 16-lane group reads the same 80 B; L1
//   absorbs redundancy but issue slots are not free).
// - Nontemporal output store: 27 MB with no reuse, keep L2/L3 for table.
__global__ __launch_bounds__(256) void emb_fwd_kernel(
    const int*   __restrict__ keys,   // [ROWS, MAX_NNZ]
    const int*   __restrict__ mask,   // [ROWS, MAX_NNZ] (0/1)
    const float* __restrict__ table,  // [VOCAB, EMB]
    float*       __restrict__ out)    // [ROWS, EMB]
{
    int tid = blockIdx.x * blockDim.x + threadIdx.x;
    int row = tid >> 4;        // 16 lanes per row
    int e4  = tid & 15;        // which float4 of the 64-float row
    if (row >= ROWS) return;

    const int* kp = keys + (size_t)row * MAX_NNZ;
    const int* mp = mask + (size_t)row * MAX_NNZ;

    // Vectorized loads: [ROWS,10] int32 rows are 40 B, 8-byte aligned at
    // row granularity (40 = 8*5), so int2-granule access is safe; int4
    // loads need 16B alignment which only holds for even rows — use
    // int2 x5 to stay alignment-safe for every row.
    intx2 k01 = *(const intx2*)(kp + 0);
    intx2 k23 = *(const intx2*)(kp + 2);
    intx2 k45 = *(const intx2*)(kp + 4);
    intx2 k67 = *(const intx2*)(kp + 6);
    intx2 k89 = *(const intx2*)(kp + 8);
    intx2 m01 = *(const intx2*)(mp + 0);
    intx2 m23 = *(const intx2*)(mp + 2);
    intx2 m45 = *(const intx2*)(mp + 4);
    intx2 m67 = *(const intx2*)(mp + 6);
    intx2 m89 = *(const intx2*)(mp + 8);

    int kk[MAX_NNZ] = {k01.x, k01.y, k23.x, k23.y, k45.x,
                       k45.y, k67.x, k67.y, k89.x, k89.y};
    int mm[MAX_NNZ] = {m01.x, m01.y, m23.x, m23.y, m45.x,
                       m45.y, m67.x, m67.y, m89.x, m89.y};

    // Redirect masked-out gathers to row 0 (hot in L1). Branch-free.
#pragma unroll
    for (int j = 0; j < MAX_NNZ; ++j) {
        kk[j] = mm[j] ? kk[j] : 0;
    }

    // Issue ALL gathers before consuming any — 10 outstanding 16B loads
    // per thread.
    floatx4 v[MAX_NNZ];
#pragma unroll
    for (int j = 0; j < MAX_NNZ; ++j) {
        const floatx4* rowp = (const floatx4*)(table + (size_t)kk[j] * EMB);
        v[j] = rowp[e4];       // coalesced 256B across the 16 lanes
    }

    floatx4 acc = (floatx4){0.f, 0.f, 0.f, 0.f};
    int cnt = 0;
#pragma unroll
    for (int j = 0; j < MAX_NNZ; ++j) {
        float w = (float)(mm[j] != 0);
        cnt += (mm[j] != 0);
        acc += w * v[j];
    }

    // mean combiner: divide by max(count, 1)
    float inv = 1.0f / (float)(cnt > 0 ? cnt : 1);
    acc *= inv;

    // Streaming store — output has no reuse; keep L2/L3 for the table.
    floatx4* op = (floatx4*)(out + (size_t)row * EMB) + e4;
    __builtin_nontemporal_store(acc, op);
}

extern "C" void kernel_launch(void* const* d_in, const int* in_sizes, int n_in,
                              void* d_out, int out_size, void* d_ws, size_t ws_size,
                              hipStream_t stream) {
    const int*   keys  = (const int*)d_in[0];
    const int*   mask  = (const int*)d_in[1];
    const float* table = (const float*)d_in[2];
    float*       out   = (float*)d_out;

    const int threads_per_row = 16;
    const int block = 256;
    const long long total_threads = (long long)ROWS * threads_per_row;
    const int grid = (int)((total_threads + block - 1) / block);   // 6656 blocks

    emb_fwd_kernel<<<grid, block, 0, stream>>>(keys, mask, table, out);
}